// Round 2
// baseline (300.180 us; speedup 1.0000x reference)
//
#include <hip/hip_runtime.h>
#include <math.h>

#define BB 8192
#define KK 32
#define DD 129      // hyperboloid dim = D + 1
#define VV 2048
#define NN 33       // K + 1
#define TOPK 10

__device__ __forceinline__ float fast_rcp(float x) { return __builtin_amdgcn_rcpf(x); }

__global__ __launch_bounds__(256) void lr_fused(
    const float* __restrict__ anchor,
    const float* __restrict__ positive,
    const float* __restrict__ neg,
    const float* __restrict__ tree,
    const int* __restrict__ a_idx,
    const int* __restrict__ p_idx,
    const int* __restrict__ n_idx,
    float* __restrict__ out)
{
    __shared__ float  st_[NN];
    __shared__ float  sd[NN];
    __shared__ float4 sitem[NN];   // {d, rel, disc, 0}
    __shared__ float  sinv;
    __shared__ float  swave[4];

    const int b    = blockIdx.x;
    const int t    = threadIdx.x;
    const int wave = t >> 6;
    const int lane = t & 63;
    const int g    = lane >> 4;    // 4 row-groups per wave
    const int subl = lane & 15;    // 16 lanes per row

    // ---- tree-distance gather (33 random dwords, L2/L3-resident table) ----
    if (t < NN) {
        int ai = a_idx[b];
        st_[t] = (t == 0)
            ? tree[(size_t)ai * VV + p_idx[b]]
            : tree[(size_t)ai * VV + n_idx[(size_t)b * KK + (t - 1)]];
    }

    // ---- anchor fragment in registers: lane holds a[16e + subl], e=0..7 ----
    const float* abase = anchor + (size_t)b * DD;
    float areg[8];
    #pragma unroll
    for (int e = 0; e < 8; ++e) areg[e] = abase[e * 16 + subl];

    // ---- Lorentz distances straight from global (coalesced, no LDS staging) ----
    #pragma unroll
    for (int round = 0; round < 3; ++round) {
        int row = round * 16 + wave * 4 + g;
        if (row < NN) {
            const float* r = (row == 0)
                ? (positive + (size_t)b * DD)
                : (neg + (size_t)b * (KK * DD) + (size_t)(row - 1) * DD);
            float s = 0.0f;
            #pragma unroll
            for (int e = 0; e < 8; ++e) s = fmaf(areg[e], r[e * 16 + subl], s);
            s += __shfl_xor(s, 8, 64);
            s += __shfl_xor(s, 4, 64);
            s += __shfl_xor(s, 2, 64);
            s += __shfl_xor(s, 1, 64);
            if (subl == 0) {
                float full = s + abase[128] * r[128];        // sum_{0..128} a*v
                // -inner = u0*v0 - sum_{1..128} = 2*u0*v0 - full
                float x = fmaxf(2.0f * areg[0] * r[0] - full, 1.0f + 1e-07f);
                // acosh(x) = log(x + sqrt(x^2 - 1)); fast v_log path
                sd[row] = __logf(x + sqrtf(x * x - 1.0f));
            }
        }
    }
    __syncthreads();

    // ---- rel, rank -> disc (stable ties = jnp stable argsort) ----
    if (t < NN) {
        float maxt = st_[0];
        #pragma unroll
        for (int j = 1; j < NN; ++j) maxt = fmaxf(maxt, st_[j]);
        float rel = (maxt - st_[t] + 1e-06f) * fast_rcp(maxt + 1e-06f);

        float di = sd[t];
        int cnt = 0;
        #pragma unroll
        for (int j = 0; j < NN; ++j) {
            float dj = sd[j];
            cnt += (int)((dj < di) | ((dj == di) & (j < t)));
        }
        int rank = cnt + 1;
        float disc = (rank <= TOPK) ? fast_rcp(log2f((float)(rank + 1))) : 0.0f;
        sitem[t] = make_float4(di, rel, disc, 0.0f);
    }
    __syncthreads();

    // ---- IDCG on wave 0 (stable descending position count + wave reduce) ----
    if (wave == 0) {
        float c = 0.0f;
        if (t < NN) {
            float ri = sitem[t].y;
            int pos = 0;
            #pragma unroll
            for (int j = 0; j < NN; ++j) {
                float rj = sitem[j].y;
                pos += (int)((rj > ri) | ((rj == ri) & (j < t)));
            }
            if (pos < TOPK) c = ri * fast_rcp(log2f((float)(pos + 2)));
        }
        #pragma unroll
        for (int off = 32; off > 0; off >>= 1) c += __shfl_xor(c, off, 64);
        if (t == 0) sinv = (c > 0.0f) ? fast_rcp(c) : 0.0f;
    }
    __syncthreads();

    // ---- 33x33 pair sum: term = S*delta*sigmoid(S*dd)*(-dd) ----
    //      S*delta = drel*|ddisc|*inv ; sigmoid(S*dd) = (drel>=0 ? 1 : e)/(1+e), e=exp(-dd)
    float acc = 0.0f;
    {
        const float inv = sinv;
        for (int p = t; p < NN * NN; p += 256) {
            int i = p / NN;
            int j = p - i * NN;
            float4 Ii = sitem[i];
            float4 Ij = sitem[j];
            float dd    = Ij.x - Ii.x;         // d[j] - d[i]
            float drel  = Ii.y - Ij.y;
            float ddisc = Ii.z - Ij.z;
            float t1  = drel * fabsf(ddisc) * inv;     // S * delta
            float e   = __expf(-dd);
            float num = (drel >= 0.0f) ? 1.0f : e;
            acc = fmaf(t1 * num * fast_rcp(1.0f + e), -dd, acc);
        }
    }
    #pragma unroll
    for (int off = 32; off > 0; off >>= 1) acc += __shfl_xor(acc, off, 64);
    if (lane == 0) swave[wave] = acc;
    __syncthreads();
    if (t == 0) {
        float v = (swave[0] + swave[1] + swave[2] + swave[3])
                  * (0.5f * 0.15f / (float)BB);
        atomicAdd(out, v);
    }
}

extern "C" void kernel_launch(void* const* d_in, const int* in_sizes, int n_in,
                              void* d_out, int out_size, void* d_ws, size_t ws_size,
                              hipStream_t stream)
{
    const float* anchor   = (const float*)d_in[0];
    const float* positive = (const float*)d_in[1];
    const float* neg      = (const float*)d_in[2];
    const float* tree     = (const float*)d_in[3];
    const int*   a_idx    = (const int*)d_in[4];
    const int*   p_idx    = (const int*)d_in[5];
    const int*   n_idx    = (const int*)d_in[6];

    hipMemsetAsync(d_out, 0, (size_t)out_size * sizeof(float), stream);
    lr_fused<<<BB, 256, 0, stream>>>(anchor, positive, neg, tree,
                                     a_idx, p_idx, n_idx, (float*)d_out);
}

// Round 3
// 237.333 us; speedup vs baseline: 1.2648x; 1.2648x over previous
//
#include <hip/hip_runtime.h>
#include <math.h>

#define BB 8192
#define KK 32
#define DD 129      // hyperboloid dim = D + 1
#define VV 2048
#define NN 33       // K + 1
#define TOPK 10

__device__ __forceinline__ float fast_rcp(float x) { return __builtin_amdgcn_rcpf(x); }

__global__ __launch_bounds__(256) void lr_main(
    const float* __restrict__ anchor,
    const float* __restrict__ positive,
    const float* __restrict__ neg,
    const float* __restrict__ tree,
    const int* __restrict__ a_idx,
    const int* __restrict__ p_idx,
    const int* __restrict__ n_idx,
    float* __restrict__ partial)
{
    __shared__ float  sA[DD];
    __shared__ float  sP[DD];
    __shared__ float  sR[KK * DD];     // 4128 floats = 16.5 KB
    __shared__ float  st_[NN];
    __shared__ float  sd[NN];
    __shared__ float4 sitem[NN];       // {d, rel, disc, 0}
    __shared__ float  sinv;
    __shared__ float  swave[4];

    const int b    = blockIdx.x;
    const int t    = threadIdx.x;
    const int wave = t >> 6;
    const int lane = t & 63;
    const int g    = lane >> 4;        // 4 row-groups per wave
    const int subl = lane & 15;        // 16 lanes per row

    // ---- stage: neg tile as float4 (16512 B/batch is 16B-aligned), a/p scalar ----
    {
        const float4* g4 = (const float4*)(neg + (size_t)b * (KK * DD));
        float4* s4 = (float4*)sR;
        #pragma unroll
        for (int c = 0; c < 5; ++c) {
            int i = c * 256 + t;
            if (i < (KK * DD) / 4) s4[i] = g4[i];
        }
    }
    if (t < DD) {
        sA[t] = anchor[(size_t)b * DD + t];
        sP[t] = positive[(size_t)b * DD + t];
    }
    if (t < NN) {
        int ai = a_idx[b];
        st_[t] = (t == 0)
            ? tree[(size_t)ai * VV + p_idx[b]]
            : tree[(size_t)ai * VV + n_idx[(size_t)b * KK + (t - 1)]];
    }
    __syncthreads();

    // ---- Lorentz distances from LDS: 16 lanes/row, 4 rows/wave/round ----
    {
        float areg[8];
        #pragma unroll
        for (int e = 0; e < 8; ++e) areg[e] = sA[e * 16 + subl];
        const float a128 = sA[128];
        const float a0   = sA[0];

        #pragma unroll
        for (int round = 0; round < 3; ++round) {
            int row = round * 16 + wave * 4 + g;
            if (row < NN) {
                const float* r = (row == 0) ? sP : (sR + (row - 1) * DD);
                float s = 0.0f;
                #pragma unroll
                for (int e = 0; e < 8; ++e) s = fmaf(areg[e], r[e * 16 + subl], s);
                s += __shfl_xor(s, 8, 64);
                s += __shfl_xor(s, 4, 64);
                s += __shfl_xor(s, 2, 64);
                s += __shfl_xor(s, 1, 64);
                if (subl == 0) {
                    float full = s + a128 * r[128];            // sum_{0..128} a*v
                    // -inner = 2*u0*v0 - full
                    float x = fmaxf(2.0f * a0 * r[0] - full, 1.0f + 1e-07f);
                    sd[row] = __logf(x + sqrtf(x * x - 1.0f)); // acosh
                }
            }
        }
    }
    __syncthreads();

    // ---- rel, stable rank -> disc (matches jnp stable argsort) ----
    if (t < NN) {
        float maxt = st_[0];
        #pragma unroll
        for (int j = 1; j < NN; ++j) maxt = fmaxf(maxt, st_[j]);
        float rel = (maxt - st_[t] + 1e-06f) * fast_rcp(maxt + 1e-06f);

        float di = sd[t];
        int cnt = 0;
        #pragma unroll
        for (int j = 0; j < NN; ++j) {
            float dj = sd[j];
            cnt += (int)((dj < di) | ((dj == di) & (j < t)));
        }
        int rank = cnt + 1;
        float disc = (rank <= TOPK) ? fast_rcp(log2f((float)(rank + 1))) : 0.0f;
        sitem[t] = make_float4(di, rel, disc, 0.0f);
    }
    __syncthreads();

    // ---- IDCG on wave 0: stable descending position + wave reduce ----
    if (wave == 0) {
        float c = 0.0f;
        if (t < NN) {
            float ri = sitem[t].y;
            int pos = 0;
            #pragma unroll
            for (int j = 0; j < NN; ++j) {
                float rj = sitem[j].y;
                pos += (int)((rj > ri) | ((rj == ri) & (j < t)));
            }
            if (pos < TOPK) c = ri * fast_rcp(log2f((float)(pos + 2)));
        }
        #pragma unroll
        for (int off = 32; off > 0; off >>= 1) c += __shfl_xor(c, off, 64);
        if (t == 0) sinv = (c > 0.0f) ? fast_rcp(c) : 0.0f;
    }
    __syncthreads();

    // ---- 33x33 pair sum ----
    // S*delta = drel*|ddisc|*inv ; sigmoid(S*dd) = (drel>=0 ? 1 : e)/(1+e), e = exp(-dd)
    float acc = 0.0f;
    {
        const float inv = sinv;
        #pragma unroll
        for (int c = 0; c < 5; ++c) {
            int p = c * 256 + t;
            if (p < NN * NN) {
                int i = p / NN;
                int j = p - i * NN;
                float4 Ii = sitem[i];
                float4 Ij = sitem[j];
                float dd    = Ij.x - Ii.x;             // d[j] - d[i]
                float drel  = Ii.y - Ij.y;
                float ddisc = Ii.z - Ij.z;
                float t1  = drel * fabsf(ddisc) * inv; // S * delta
                float e   = __expf(-dd);
                float num = (drel >= 0.0f) ? 1.0f : e;
                acc = fmaf(t1 * num * fast_rcp(1.0f + e), -dd, acc);
            }
        }
    }
    #pragma unroll
    for (int off = 32; off > 0; off >>= 1) acc += __shfl_xor(acc, off, 64);
    if (lane == 0) swave[wave] = acc;
    __syncthreads();
    if (t == 0)
        partial[b] = 0.5f * (swave[0] + swave[1] + swave[2] + swave[3]);
}

__global__ __launch_bounds__(256) void lr_reduce(
    const float* __restrict__ partial, float* __restrict__ out)
{
    __shared__ float swave[4];
    const float4* p4 = (const float4*)partial;
    float acc = 0.0f;
    #pragma unroll
    for (int c = 0; c < (BB / 4) / 256; ++c) {
        float4 v = p4[c * 256 + threadIdx.x];
        acc += (v.x + v.y) + (v.z + v.w);
    }
    #pragma unroll
    for (int off = 32; off > 0; off >>= 1) acc += __shfl_xor(acc, off, 64);
    if ((threadIdx.x & 63) == 0) swave[threadIdx.x >> 6] = acc;
    __syncthreads();
    if (threadIdx.x == 0)
        out[0] = (swave[0] + swave[1] + swave[2] + swave[3]) * (0.15f / (float)BB);
}

extern "C" void kernel_launch(void* const* d_in, const int* in_sizes, int n_in,
                              void* d_out, int out_size, void* d_ws, size_t ws_size,
                              hipStream_t stream)
{
    const float* anchor   = (const float*)d_in[0];
    const float* positive = (const float*)d_in[1];
    const float* neg      = (const float*)d_in[2];
    const float* tree     = (const float*)d_in[3];
    const int*   a_idx    = (const int*)d_in[4];
    const int*   p_idx    = (const int*)d_in[5];
    const int*   n_idx    = (const int*)d_in[6];
    float* partial = (float*)d_ws;   // BB floats = 32 KB scratch

    lr_main<<<BB, 256, 0, stream>>>(anchor, positive, neg, tree,
                                    a_idx, p_idx, n_idx, partial);
    lr_reduce<<<1, 256, 0, stream>>>(partial, (float*)d_out);
}

// Round 4
// 224.509 us; speedup vs baseline: 1.3371x; 1.0571x over previous
//
#include <hip/hip_runtime.h>
#include <math.h>

#define BB 8192
#define KK 32
#define DD 129      // hyperboloid dim = D + 1
#define VV 2048
#define NN 33       // K + 1
#define TOPK 10
#define WPB 4       // waves (= batches) per block

__device__ __forceinline__ float fast_rcp(float x) { return __builtin_amdgcn_rcpf(x); }

__global__ __launch_bounds__(256) void lr_fused(
    const float* __restrict__ anchor,
    const float* __restrict__ positive,
    const float* __restrict__ neg,
    const float* __restrict__ tree,
    const int* __restrict__ a_idx,
    const int* __restrict__ p_idx,
    const int* __restrict__ n_idx,
    float* __restrict__ partial)
{
    __shared__ float  st_[WPB][NN];
    __shared__ float  sd_[WPB][NN];
    __shared__ float4 sitem[WPB][NN];   // {d, rel, disc, 0}

    const int t    = threadIdx.x;
    const int wave = t >> 6;
    const int lane = t & 63;
    const int g    = lane >> 4;        // 4 row-groups per wave
    const int subl = lane & 15;        // 16 lanes per row
    const int b    = blockIdx.x * WPB + wave;

    // ================= Phase A: issue ALL global loads as one burst =========
    // tree gather (all 64 lanes, lanes >=33 clamped & discarded)
    const int ai  = a_idx[b];
    const int col = (lane == 0) ? p_idx[b]
                                : n_idx[(size_t)b * KK + ((lane < NN ? lane : KK) - 1)];
    const float tg = tree[(size_t)ai * VV + col];

    const float* ab = anchor   + (size_t)b * DD;
    const float* pb = positive + (size_t)b * DD;
    const float* nb = neg      + (size_t)b * (KK * DD);

    float areg[8];
    #pragma unroll
    for (int e = 0; e < 8; ++e) areg[e] = ab[e * 16 + subl];
    const float a128 = ab[128];

    // 9 rounds x 4 row-groups covers rows 0..35 (33..35 clamped to 32)
    const float* rp[9];
    #pragma unroll
    for (int r = 0; r < 9; ++r) {
        int row = 4 * r + g;
        if (row > KK) row = KK;
        rp[r] = (row == 0) ? pb : (nb + (size_t)(row - 1) * DD);
    }
    float vv[9][8];
    #pragma unroll
    for (int r = 0; r < 9; ++r)
        #pragma unroll
        for (int e = 0; e < 8; ++e)
            vv[r][e] = rp[r][e * 16 + subl];
    float t128[9];
    #pragma unroll
    for (int r = 0; r < 9; ++r) t128[r] = rp[r][128];

    // park the tree gather in LDS
    if (lane < NN) st_[wave][lane] = tg;

    // ---- Lorentz distances: 16 lanes/row dot + 4-step shuffle reduce ----
    #pragma unroll
    for (int r = 0; r < 9; ++r) {
        float s = 0.0f;
        #pragma unroll
        for (int e = 0; e < 8; ++e) s = fmaf(areg[e], vv[r][e], s);
        s += __shfl_xor(s, 8, 64);
        s += __shfl_xor(s, 4, 64);
        s += __shfl_xor(s, 2, 64);
        s += __shfl_xor(s, 1, 64);
        int row = 4 * r + g;
        if (subl == 0 && row < NN) {
            float full = s + a128 * t128[r];                 // sum_{0..128} a*v
            // -inner = 2*u0*v0 - full   (u0 = areg[0], v0 = vv[r][0] at subl==0)
            float x = fmaxf(fmaf(2.0f * areg[0], vv[r][0], -full), 1.0f + 1e-07f);
            sd_[wave][row] = __logf(x + sqrtf(x * x - 1.0f)); // acosh
        }
    }
    __syncthreads();

    // ============ Phase B: rel, stable rank -> disc (per wave) =============
    if (lane < NN) {
        float maxt = st_[wave][0];
        #pragma unroll
        for (int j = 1; j < NN; ++j) maxt = fmaxf(maxt, st_[wave][j]);
        float rel = (maxt - st_[wave][lane] + 1e-06f) * fast_rcp(maxt + 1e-06f);

        float di = sd_[wave][lane];
        int cnt = 0;
        #pragma unroll
        for (int j = 0; j < NN; ++j) {
            float dj = sd_[wave][j];
            cnt += (int)((dj < di) | ((dj == di) & (j < lane)));
        }
        // rank = cnt+1 ; disc = rank<=10 ? 1/log2(rank+1) : 0
        float disc = (cnt + 1 <= TOPK) ? fast_rcp(log2f((float)(cnt + 2))) : 0.0f;
        sitem[wave][lane] = make_float4(di, rel, disc, 0.0f);
    }
    __syncthreads();

    // ============ Phase C: IDCG (stable descending pos) -> inv in regs =====
    float c = 0.0f;
    if (lane < NN) {
        float ri = sitem[wave][lane].y;
        int pos = 0;
        #pragma unroll
        for (int j = 0; j < NN; ++j) {
            float rj = sitem[wave][j].y;
            pos += (int)((rj > ri) | ((rj == ri) & (j < lane)));
        }
        if (pos < TOPK) c = ri * fast_rcp(log2f((float)(pos + 2)));
    }
    #pragma unroll
    for (int off = 32; off > 0; off >>= 1) c += __shfl_xor(c, off, 64);
    const float inv = (c > 0.0f) ? fast_rcp(c) : 0.0f;   // all lanes hold it

    // ============ Phase D: 33x33 pair sum (diagonal term p=1088 is 0) ======
    // S*delta = drel*|ddisc|*inv ; sigmoid(S*dd) = (drel>=0 ? 1 : e)/(1+e), e=exp(-dd)
    float acc = 0.0f;
    #pragma unroll
    for (int it = 0; it < 17; ++it) {
        int p = it * 64 + lane;            // 0..1087
        int i = p / NN;
        int j = p - i * NN;
        float4 Ii = sitem[wave][i];
        float4 Ij = sitem[wave][j];
        float dd    = Ij.x - Ii.x;         // d[j] - d[i]
        float drel  = Ii.y - Ij.y;
        float ddisc = Ii.z - Ij.z;
        float t1  = drel * fabsf(ddisc) * inv;   // S * delta
        float e   = __expf(-dd);
        float num = (drel >= 0.0f) ? 1.0f : e;
        acc = fmaf(t1 * num * fast_rcp(1.0f + e), -dd, acc);
    }
    #pragma unroll
    for (int off = 32; off > 0; off >>= 1) acc += __shfl_xor(acc, off, 64);
    if (lane == 0) partial[b] = 0.5f * acc;
}

__global__ __launch_bounds__(256) void lr_reduce(
    const float* __restrict__ partial, float* __restrict__ out)
{
    __shared__ float swave[4];
    const float4* p4 = (const float4*)partial;
    float acc = 0.0f;
    #pragma unroll
    for (int c = 0; c < (BB / 4) / 256; ++c) {
        float4 v = p4[c * 256 + threadIdx.x];
        acc += (v.x + v.y) + (v.z + v.w);
    }
    #pragma unroll
    for (int off = 32; off > 0; off >>= 1) acc += __shfl_xor(acc, off, 64);
    if ((threadIdx.x & 63) == 0) swave[threadIdx.x >> 6] = acc;
    __syncthreads();
    if (threadIdx.x == 0)
        out[0] = (swave[0] + swave[1] + swave[2] + swave[3]) * (0.15f / (float)BB);
}

extern "C" void kernel_launch(void* const* d_in, const int* in_sizes, int n_in,
                              void* d_out, int out_size, void* d_ws, size_t ws_size,
                              hipStream_t stream)
{
    const float* anchor   = (const float*)d_in[0];
    const float* positive = (const float*)d_in[1];
    const float* neg      = (const float*)d_in[2];
    const float* tree     = (const float*)d_in[3];
    const int*   a_idx    = (const int*)d_in[4];
    const int*   p_idx    = (const int*)d_in[5];
    const int*   n_idx    = (const int*)d_in[6];
    float* partial = (float*)d_ws;   // BB floats = 32 KB scratch

    lr_fused<<<BB / WPB, 256, 0, stream>>>(anchor, positive, neg, tree,
                                           a_idx, p_idx, n_idx, partial);
    lr_reduce<<<1, 256, 0, stream>>>(partial, (float*)d_out);
}

// Round 5
// 222.158 us; speedup vs baseline: 1.3512x; 1.0106x over previous
//
#include <hip/hip_runtime.h>
#include <math.h>

#define BB 8192
#define KK 32
#define DD 129      // hyperboloid dim = D + 1
#define VV 2048
#define NN 33       // K + 1
#define TOPK 10
#define WPB 4       // waves (= batches) per block; waves are fully autonomous (no barriers)

__device__ __forceinline__ float fast_rcp(float x) { return __builtin_amdgcn_rcpf(x); }

__global__ __launch_bounds__(256) void lr_fused(
    const float* __restrict__ anchor,
    const float* __restrict__ positive,
    const float* __restrict__ neg,
    const float* __restrict__ tree,
    const int* __restrict__ a_idx,
    const int* __restrict__ p_idx,
    const int* __restrict__ n_idx,
    float* __restrict__ partial)
{
    // all slices are per-wave private: no __syncthreads anywhere
    __shared__ float  st_[WPB][NN];     // tree distances t
    __shared__ float  sx_[WPB][NN];     // raw -inner (pre-acosh)
    __shared__ float  sd_[WPB][NN];     // d
    __shared__ float4 sitem[WPB][NN];   // {d, rel, disc, 0}

    const int t    = threadIdx.x;
    const int wave = t >> 6;
    const int lane = t & 63;
    const int g    = lane >> 4;        // 4 row-groups per wave
    const int subl = lane & 15;        // 16 lanes per row
    const int b    = blockIdx.x * WPB + wave;

    // ---- tree gather (lanes >=33 read a clamped dup, discarded) ----
    const int ai  = a_idx[b];
    const int col = (lane == 0) ? p_idx[b]
                                : n_idx[(size_t)b * KK + ((lane < NN ? lane : KK) - 1)];
    const float tg = tree[(size_t)ai * VV + col];
    if (lane < NN) st_[wave][lane] = tg;

    const float* ab = anchor   + (size_t)b * DD;
    const float* pb = positive + (size_t)b * DD;
    const float* nb = neg      + (size_t)b * (KK * DD);

    float areg[8];
    #pragma unroll
    for (int e = 0; e < 8; ++e) areg[e] = ab[e * 16 + subl];
    const float a128 = ab[128];

    // ---- burst-load all 33 rows (9 rounds x 4 groups, rows >32 clamped) ----
    const float* rp[9];
    #pragma unroll
    for (int r = 0; r < 9; ++r) {
        int row = 4 * r + g;
        if (row > KK) row = KK;
        rp[r] = (row == 0) ? pb : (nb + (size_t)(row - 1) * DD);
    }
    float vv[9][8];
    float t128[9];
    #pragma unroll
    for (int r = 0; r < 9; ++r) {
        #pragma unroll
        for (int e = 0; e < 8; ++e) vv[r][e] = rp[r][e * 16 + subl];
        t128[r] = rp[r][128];
    }

    // ---- dots: 16 lanes/row + 4-step shuffle; park raw -inner in LDS ----
    #pragma unroll
    for (int r = 0; r < 9; ++r) {
        float s = 0.0f;
        #pragma unroll
        for (int e = 0; e < 8; ++e) s = fmaf(areg[e], vv[r][e], s);
        s += __shfl_xor(s, 8, 64);
        s += __shfl_xor(s, 4, 64);
        s += __shfl_xor(s, 2, 64);
        s += __shfl_xor(s, 1, 64);
        int row = 4 * r + g;
        if (subl == 0 && row < NN) {
            float full = s + a128 * t128[r];          // sum_{0..128} a*v
            // -inner = 2*u0*v0 - full
            sx_[wave][row] = fmaxf(fmaf(2.0f * areg[0], vv[r][0], -full), 1.0f + 1e-07f);
        }
    }

    // ---- dense acosh pass (one shot, 33/64 lanes) ----
    float dlane = 0.0f;
    if (lane < NN) {
        float x = sx_[wave][lane];
        dlane = __logf(x + sqrtf(x * x - 1.0f));      // acosh(x)
        sd_[wave][lane] = dlane;
    }

    // ---- rel + stable rank -> disc (broadcast LDS reads, uniform j) ----
    if (lane < NN) {
        float maxt = st_[wave][0];
        #pragma unroll
        for (int j = 1; j < NN; ++j) maxt = fmaxf(maxt, st_[wave][j]);
        float rel = (maxt - tg + 1e-06f) * fast_rcp(maxt + 1e-06f);

        int cnt = 0;
        #pragma unroll
        for (int j = 0; j < NN; ++j) {
            float dj = sd_[wave][j];
            cnt += (int)((dj < dlane) | ((dj == dlane) & (j < lane)));
        }
        float disc = (cnt + 1 <= TOPK) ? fast_rcp(log2f((float)(cnt + 2))) : 0.0f;
        sitem[wave][lane] = make_float4(dlane, rel, disc, 0.0f);
    }

    // ---- IDCG: stable descending position, butterfly sum -> inv in regs ----
    float c = 0.0f;
    if (lane < NN) {
        float ri = sitem[wave][lane].y;
        int pos = 0;
        #pragma unroll
        for (int j = 0; j < NN; ++j) {
            float rj = sitem[wave][j].y;               // uniform j: broadcast
            pos += (int)((rj > ri) | ((rj == ri) & (j < lane)));
        }
        if (pos < TOPK) c = ri * fast_rcp(log2f((float)(pos + 2)));
    }
    #pragma unroll
    for (int off = 32; off > 0; off >>= 1) c += __shfl_xor(c, off, 64);
    const float inv = (c > 0.0f) ? fast_rcp(c) : 0.0f;

    // ---- pair sum over i<j only (term is symmetric: full sum = 2*this) ----
    // 528 pairs; p = j*(j-1)/2 + i. Exact fp32 triangular decode.
    float acc = 0.0f;
    #pragma unroll
    for (int it = 0; it < 9; ++it) {
        int p = it * 64 + lane;                  // 0..575
        float vmask = (p < 528) ? 1.0f : 0.0f;
        int pc = (p < 528) ? p : 527;
        int j = (int)((1.0f + sqrtf((float)(8 * pc + 1))) * 0.5f);
        int tj = (j * (j - 1)) >> 1;
        if (tj > pc) { --j; tj = (j * (j - 1)) >> 1; }   // safety guard
        int i = pc - tj;
        float4 Ii = sitem[wave][i];
        float4 Ij = sitem[wave][j];
        float dd    = Ij.x - Ii.x;               // d[j] - d[i]
        float drel  = Ii.y - Ij.y;
        float ddisc = Ii.z - Ij.z;
        float t1  = drel * fabsf(ddisc) * (inv * vmask);   // S * delta (masked)
        float e   = __expf(-dd);
        float num = (drel >= 0.0f) ? 1.0f : e;
        acc = fmaf(t1 * num * fast_rcp(1.0f + e), -dd, acc);
    }
    #pragma unroll
    for (int off = 32; off > 0; off >>= 1) acc += __shfl_xor(acc, off, 64);
    // 0.5 * full-sum = sum over i<j = acc
    if (lane == 0) partial[b] = acc;
}

__global__ __launch_bounds__(256) void lr_reduce(
    const float* __restrict__ partial, float* __restrict__ out)
{
    __shared__ float swave[4];
    const float4* p4 = (const float4*)partial;
    float acc = 0.0f;
    #pragma unroll
    for (int c = 0; c < (BB / 4) / 256; ++c) {
        float4 v = p4[c * 256 + threadIdx.x];
        acc += (v.x + v.y) + (v.z + v.w);
    }
    #pragma unroll
    for (int off = 32; off > 0; off >>= 1) acc += __shfl_xor(acc, off, 64);
    if ((threadIdx.x & 63) == 0) swave[threadIdx.x >> 6] = acc;
    __syncthreads();
    if (threadIdx.x == 0)
        out[0] = (swave[0] + swave[1] + swave[2] + swave[3]) * (0.15f / (float)BB);
}

extern "C" void kernel_launch(void* const* d_in, const int* in_sizes, int n_in,
                              void* d_out, int out_size, void* d_ws, size_t ws_size,
                              hipStream_t stream)
{
    const float* anchor   = (const float*)d_in[0];
    const float* positive = (const float*)d_in[1];
    const float* neg      = (const float*)d_in[2];
    const float* tree     = (const float*)d_in[3];
    const int*   a_idx    = (const int*)d_in[4];
    const int*   p_idx    = (const int*)d_in[5];
    const int*   n_idx    = (const int*)d_in[6];
    float* partial = (float*)d_ws;   // BB floats = 32 KB scratch

    lr_fused<<<BB / WPB, 256, 0, stream>>>(anchor, positive, neg, tree,
                                           a_idx, p_idx, n_idx, partial);
    lr_reduce<<<1, 256, 0, stream>>>(partial, (float*)d_out);
}